// Round 6
// baseline (953.705 us; speedup 1.0000x reference)
//
#include <hip/hip_runtime.h>
#include <hip/hip_bf16.h>

#define NEG 0.01f

using f32x4  = __attribute__((ext_vector_type(4))) float;
using bf16x8 = __attribute__((ext_vector_type(8))) short;

__device__ __forceinline__ unsigned short f2b(float f) {
  union { float f; unsigned int u; } v; v.f = f;
  unsigned int r = (v.u + 0x7fffu + ((v.u >> 16) & 1u)) >> 16;
  return (unsigned short)r;
}
__device__ __forceinline__ float b2f(unsigned int bits) {
  union { unsigned int u; float f; } v; v.u = bits << 16;
  return v.f;
}

__device__ __forceinline__ void gload16(const unsigned short* g, unsigned short* l) {
  __builtin_amdgcn_global_load_lds(
      (const __attribute__((address_space(1))) unsigned int*)g,
      (__attribute__((address_space(3))) unsigned int*)l, 16, 0, 0);
}

// ---- fp32 -> bf16 bulk convert ----
__global__ void k_cvt(const float* __restrict__ in, unsigned short* __restrict__ out, int n4) {
  int i = blockIdx.x * blockDim.x + threadIdx.x;
  int stride = gridDim.x * blockDim.x;
  for (; i < n4; i += stride) {
    float4 v = reinterpret_cast<const float4*>(in)[i];
    ushort4 o;
    o.x = f2b(v.x); o.y = f2b(v.y); o.z = f2b(v.z); o.w = f2b(v.w);
    reinterpret_cast<ushort4*>(out)[i] = o;
  }
}

// ---- triangular-masked weight convert (anti=1 folds the layer-2 flip) ----
__global__ void k_cvt_tri(const float* __restrict__ W, unsigned short* __restrict__ out, int anti) {
  const int H = 2048;
  int i = blockIdx.x;
  const float* wr = W + (size_t)i * H;
  unsigned short* orow = out + (size_t)i * H;
  if (!anti) {
    for (int j = threadIdx.x; j < H; j += blockDim.x) {
      float v = (j >= i) ? wr[j] : 0.f;
      orow[j] = f2b(v);
    }
  } else {
    for (int k = threadIdx.x; k < H; k += blockDim.x) {
      int j = H - 1 - k;
      float v = (j >= i) ? wr[j] : 0.f;
      orow[k] = f2b(v);
    }
  }
}

// ---- persistent-block phased bf16 MFMA GEMM, C = lrelu(A @ B^T + bias), bf16 out.
// Tile 256x256, BK=64, 512 thr = 8 waves (2 row-halves x 4 col-quarters),
// wave tile 128x64.  LDS 2x64KB dbuf.  Grid = 256 persistent blocks (1/CU);
// K-depth balance: nt(bx)=32-4*bx for tri modes, pairs (bx,7-bx) sum to 36
// K-tiles -> block b owns pairs p = b, b+256, ...: exactly equal work/CU.
// Per K-tile: 4 quadrant phases (0,0)->(0,1)->(1,1)->(1,0), 28 ds_read_b128
// (aR reused across nh, bR across mh where order permits), 4 barriers,
// stage(t+2) issued in P3 overlapped with MFMA, counted vmcnt(8) gate.
// Stage safety: all buf-bb reads retire before each wave's P2 lgkmcnt(0);
// stage issues only after exiting the P2 barrier -> no read/write race.
// LDS swizzle (verified 0 conflicts): subtile chunk (r,g) at byte
// r*64 + ((g+(r>>1))&3)*16; write side realized by pre-rotating the per-lane
// global source k-slot (gload_lds writes linearly).
// mode: 0=full K, 1=upper-tri (kstart=bcol), 2=anti (kend=K-bcol) ----
__launch_bounds__(512, 2)
__global__ void k_gemm8(const unsigned short* __restrict__ A, int lda,
                        const unsigned short* __restrict__ B, int ldb,
                        const float* __restrict__ bias,
                        unsigned short* __restrict__ C, int ldc,
                        int K, int mode, int NB) {
  extern __shared__ unsigned short lds[];
  const int tid = threadIdx.x;
  const int w   = tid >> 6;
  const int l   = tid & 63;

  // XCD-ownership swizzle: XCD c owns b in [c*32, c*32+32) -> contiguous by-rows
  const int G = gridDim.x;            // 256
  const int P = blockIdx.x;
  const int b = (P & 7) * (G >> 3) + (P >> 3);

  const int srow  = l >> 2;
  const int sperm = ((l & 3) - ((l >> 3) & 3)) & 3;
  const int rdoff = (l & 15) * 64 + ((((l >> 4) + ((l >> 1) & 7)) & 3) << 4);
  const int wm = w >> 2, wn = w & 3;
  const int AbaseW = wm * 16384;
  const int BbaseW = 32768 + (wn >> 1) * 16384 + (wn & 1) * 8192;

  const int npairs = NB * 4;
#pragma unroll 1
  for (int p = b; p < npairs; p += G) {
    const int by = p >> 2;
    const int pr = p & 3;
#pragma unroll 1
    for (int side = 0; side < 2; side++) {
      const int bx = side ? (7 - pr) : pr;   // deeper tile first
      const int brow = by * 256;
      const int bcol = bx * 256;
      int kstart = 0, kend = K;
      if (mode == 1) kstart = bcol;
      else if (mode == 2) kend = K - bcol;
      const int nt = (kend - kstart) >> 6;   // >= 1 always

      const unsigned short* Asrc = A + (size_t)(brow + w * 16 + srow) * lda + sperm * 8;
      const unsigned short* Bsrc = B + (size_t)(bcol + w * 16 + srow) * ldb + sperm * 8;

      auto stage_tile = [&](int tk, int bb) {
        const int kc = kstart + (tk << 6);
#pragma unroll
        for (int half = 0; half < 2; half++) {
#pragma unroll
          for (int qq = 0; qq < 2; qq++) {
            gload16(Asrc + (size_t)(half * 128) * lda + kc + qq * 32,
                    (unsigned short*)((char*)lds + bb * 65536 + half * 16384 + (w * 2 + qq) * 1024));
            gload16(Bsrc + (size_t)(half * 128) * ldb + kc + qq * 32,
                    (unsigned short*)((char*)lds + bb * 65536 + 32768 + half * 16384 + (w * 2 + qq) * 1024));
          }
        }
      };

      f32x4 acc[8][4];
#pragma unroll
      for (int i = 0; i < 8; i++)
#pragma unroll
        for (int j = 0; j < 4; j++) acc[i][j] = (f32x4){0.f, 0.f, 0.f, 0.f};

      stage_tile(0, 0);
      if (nt > 1) stage_tile(1, 1);

#pragma unroll 1
      for (int t = 0; t < nt; t++) {
        const int bb = t & 1;
        const char* Ab = (const char*)lds + bb * 65536 + AbaseW;
        const char* Bb = (const char*)lds + bb * 65536 + BbaseW;
        if (t + 1 < nt) asm volatile("s_waitcnt vmcnt(8)" ::: "memory");
        else            asm volatile("s_waitcnt vmcnt(0)" ::: "memory");
        __builtin_amdgcn_s_barrier();
        asm volatile("" ::: "memory");

        bf16x8 aR[4][2], bRa[2][2], bRb[2][2];
        // ---- P0: quad (mh0, nh0) ----
#pragma unroll
        for (int ii = 0; ii < 4; ii++)
#pragma unroll
          for (int kk = 0; kk < 2; kk++)
            aR[ii][kk] = *(const bf16x8*)(Ab + (ii * 2 + kk) * 1024 + rdoff);
#pragma unroll
        for (int jj = 0; jj < 2; jj++)
#pragma unroll
          for (int kk = 0; kk < 2; kk++)
            bRa[jj][kk] = *(const bf16x8*)(Bb + (jj * 2 + kk) * 1024 + rdoff);
        __builtin_amdgcn_s_setprio(1);
#pragma unroll
        for (int ii = 0; ii < 4; ii++)
#pragma unroll
          for (int jj = 0; jj < 2; jj++) {
            acc[ii][jj] = __builtin_amdgcn_mfma_f32_16x16x32_bf16(aR[ii][0], bRa[jj][0], acc[ii][jj], 0, 0, 0);
            acc[ii][jj] = __builtin_amdgcn_mfma_f32_16x16x32_bf16(aR[ii][1], bRa[jj][1], acc[ii][jj], 0, 0, 0);
          }
        __builtin_amdgcn_s_setprio(0);
        __builtin_amdgcn_s_barrier();
        asm volatile("" ::: "memory");
        // ---- P1: quad (mh0, nh1), reuse aR ----
#pragma unroll
        for (int jj = 0; jj < 2; jj++)
#pragma unroll
          for (int kk = 0; kk < 2; kk++)
            bRb[jj][kk] = *(const bf16x8*)(Bb + ((2 + jj) * 2 + kk) * 1024 + rdoff);
        __builtin_amdgcn_s_setprio(1);
#pragma unroll
        for (int ii = 0; ii < 4; ii++)
#pragma unroll
          for (int jj = 0; jj < 2; jj++) {
            acc[ii][2 + jj] = __builtin_amdgcn_mfma_f32_16x16x32_bf16(aR[ii][0], bRb[jj][0], acc[ii][2 + jj], 0, 0, 0);
            acc[ii][2 + jj] = __builtin_amdgcn_mfma_f32_16x16x32_bf16(aR[ii][1], bRb[jj][1], acc[ii][2 + jj], 0, 0, 0);
          }
        __builtin_amdgcn_s_setprio(0);
        __builtin_amdgcn_s_barrier();
        asm volatile("" ::: "memory");
        // ---- P2: quad (mh1, nh1), reuse bRb; prefetch bRa for P3 ----
#pragma unroll
        for (int ii = 0; ii < 4; ii++)
#pragma unroll
          for (int kk = 0; kk < 2; kk++)
            aR[ii][kk] = *(const bf16x8*)(Ab + ((4 + ii) * 2 + kk) * 1024 + rdoff);
#pragma unroll
        for (int jj = 0; jj < 2; jj++)
#pragma unroll
          for (int kk = 0; kk < 2; kk++)
            bRa[jj][kk] = *(const bf16x8*)(Bb + (jj * 2 + kk) * 1024 + rdoff);
        __builtin_amdgcn_s_setprio(1);
#pragma unroll
        for (int ii = 0; ii < 4; ii++)
#pragma unroll
          for (int jj = 0; jj < 2; jj++) {
            acc[4 + ii][2 + jj] = __builtin_amdgcn_mfma_f32_16x16x32_bf16(aR[ii][0], bRb[jj][0], acc[4 + ii][2 + jj], 0, 0, 0);
            acc[4 + ii][2 + jj] = __builtin_amdgcn_mfma_f32_16x16x32_bf16(aR[ii][1], bRb[jj][1], acc[4 + ii][2 + jj], 0, 0, 0);
          }
        __builtin_amdgcn_s_setprio(0);
        // all of this wave's buf-bb reads retired before the barrier:
        asm volatile("s_waitcnt lgkmcnt(0)" ::: "memory");
        __builtin_amdgcn_s_barrier();
        asm volatile("" ::: "memory");
        // ---- P3: quad (mh1, nh0); stage t+2 overlapped with MFMA ----
        if (t + 2 < nt) stage_tile(t + 2, bb);
        __builtin_amdgcn_s_setprio(1);
#pragma unroll
        for (int ii = 0; ii < 4; ii++)
#pragma unroll
          for (int jj = 0; jj < 2; jj++) {
            acc[4 + ii][jj] = __builtin_amdgcn_mfma_f32_16x16x32_bf16(aR[ii][0], bRa[jj][0], acc[4 + ii][jj], 0, 0, 0);
            acc[4 + ii][jj] = __builtin_amdgcn_mfma_f32_16x16x32_bf16(aR[ii][1], bRa[jj][1], acc[4 + ii][jj], 0, 0, 0);
          }
        __builtin_amdgcn_s_setprio(0);
        // next iteration's top vmcnt+barrier provides the post-P3 sync
      }

      // epilogue: bias + leaky-relu + bf16 store
      const int orow0 = brow + wm * 128 + ((l >> 4) << 2);
      const int ocol0 = bcol + wn * 64 + (l & 15);
#pragma unroll
      for (int j = 0; j < 4; j++) {
        const int col = ocol0 + j * 16;
        const float bv = bias[col];
#pragma unroll
        for (int i = 0; i < 8; i++) {
#pragma unroll
          for (int r = 0; r < 4; r++) {
            const int row = orow0 + i * 16 + r;
            float v = acc[i][j][r] + bv;
            v = v > 0.f ? v : NEG * v;
            C[(size_t)row * ldc + col] = f2b(v);
          }
        }
      }
    }
  }
}

// ---- final layer: out[n,0..2] = A[n,:] @ ow^T + ob ----
__global__ void k_out(const unsigned short* __restrict__ A,
                      const float* __restrict__ ow, const float* __restrict__ ob,
                      float* __restrict__ out) {
  const int H = 2048;
  int w = threadIdx.x >> 6, lane = threadIdx.x & 63;
  size_t n = (size_t)blockIdx.x * 4 + w;
  const unsigned short* a = A + n * H;
  float s0 = 0.f, s1 = 0.f, s2 = 0.f;
  for (int h0 = lane * 8; h0 < H; h0 += 512) {
    uint4 u = *reinterpret_cast<const uint4*>(&a[h0]);
    unsigned int uu[4] = {u.x, u.y, u.z, u.w};
#pragma unroll
    for (int q = 0; q < 4; q++) {
      int h = h0 + q * 2;
      float x0 = b2f(uu[q] & 0xffffu);
      float x1 = b2f(uu[q] >> 16);
      s0 += x0 * ow[h]         + x1 * ow[h + 1];
      s1 += x0 * ow[H + h]     + x1 * ow[H + h + 1];
      s2 += x0 * ow[2 * H + h] + x1 * ow[2 * H + h + 1];
    }
  }
#pragma unroll
  for (int off = 32; off > 0; off >>= 1) {
    s0 += __shfl_down(s0, off);
    s1 += __shfl_down(s1, off);
    s2 += __shfl_down(s2, off);
  }
  if (lane == 0) {
    out[n * 3 + 0] = s0 + ob[0];
    out[n * 3 + 1] = s1 + ob[1];
    out[n * 3 + 2] = s2 + ob[2];
  }
}

extern "C" void kernel_launch(void* const* d_in, const int* in_sizes, int n_in,
                              void* d_out, int out_size, void* d_ws, size_t ws_size,
                              hipStream_t stream) {
  const int N = 32768, H = 2048, INF_ = 64;
  const float* p      = (const float*)d_in[0];
  const float* init_w = (const float*)d_in[1];
  const float* init_b = (const float*)d_in[2];
  const float* w1     = (const float*)d_in[3];
  const float* b1     = (const float*)d_in[4];
  const float* w2     = (const float*)d_in[5];
  const float* b2     = (const float*)d_in[6];
  const float* w3     = (const float*)d_in[7];
  const float* b3     = (const float*)d_in[8];
  const float* ow     = (const float*)d_in[9];
  const float* ob     = (const float*)d_in[10];

  hipFuncSetAttribute((const void*)k_gemm8,
                      hipFuncAttributeMaxDynamicSharedMemorySize, 131072);

  char* wsb = (char*)d_ws;
  size_t off = 0;
  auto alloc = [&](size_t bytes) -> char* {
    char* q = wsb + off;
    off += (bytes + 255) & ~(size_t)255;
    return q;
  };
  unsigned short* pb  = (unsigned short*)alloc((size_t)N * INF_ * 2);
  unsigned short* iwb = (unsigned short*)alloc((size_t)H * INF_ * 2);
  unsigned short* w1m = (unsigned short*)alloc((size_t)H * H * 2);
  unsigned short* w2m = (unsigned short*)alloc((size_t)H * H * 2);
  unsigned short* w3m = (unsigned short*)alloc((size_t)H * H * 2);

  size_t remain = (ws_size > off) ? (ws_size - off) : 0;
  long long ncll = (long long)(remain / ((size_t)H * 2 * 2));
  int Nc = (int)((ncll / 256) * 256);
  if (Nc > N) Nc = N;
  if (Nc < 256) return;  // ws too small: leave d_out poisoned (clean failure)

  unsigned short* bufA = (unsigned short*)(wsb + off);
  unsigned short* bufB = bufA + (size_t)Nc * H;

  k_cvt<<<2048, 256, 0, stream>>>(p, pb, N * INF_ / 4);
  k_cvt<<<32,   256, 0, stream>>>(init_w, iwb, H * INF_ / 4);
  k_cvt_tri<<<H, 256, 0, stream>>>(w1, w1m, 0);
  k_cvt_tri<<<H, 256, 0, stream>>>(w2, w2m, 0);
  k_cvt_tri<<<H, 256, 0, stream>>>(w3, w3m, 1);

  for (int n0 = 0; n0 < N; n0 += Nc) {
    int nc = (N - n0 < Nc) ? (N - n0) : Nc;
    int NB = nc / 256;
    // layer 0: K=64 (single K-tile per tile)
    k_gemm8<<<256, 512, 131072, stream>>>(pb + (size_t)n0 * INF_, INF_, iwb, INF_,
                                          init_b, bufA, H, INF_, 0, NB);
    // layer 1 (upper-tri)
    k_gemm8<<<256, 512, 131072, stream>>>(bufA, H, w1m, H, b1, bufB, H, H, 1, NB);
    // layer 2 (upper-tri; flip folded into w3m)
    k_gemm8<<<256, 512, 131072, stream>>>(bufB, H, w2m, H, b2, bufA, H, H, 1, NB);
    // layer 3 (anti-tri, pre-flipped weights)
    k_gemm8<<<256, 512, 131072, stream>>>(bufA, H, w3m, H, b3, bufB, H, H, 2, NB);
    // out head
    k_out<<<nc / 4, 256, 0, stream>>>(bufB, ow, ob, (float*)d_out + (size_t)n0 * 3);
  }
}